// Round 1
// baseline (544.822 us; speedup 1.0000x reference)
//
#include <hip/hip_runtime.h>

typedef __bf16 bf16x8_t __attribute__((ext_vector_type(8)));
typedef float f32x4_t __attribute__((ext_vector_type(4)));
typedef unsigned short u16x8_t __attribute__((ext_vector_type(8)));
typedef unsigned short u16x4_t __attribute__((ext_vector_type(4)));

#define KDIM 512
#define UDIM 512

// ---------------------------------------------------------------------------
// Kernel 0: split W1 [E,U] f32 -> W1^T hi/lo bf16 [U,E] (truncation split)
// ---------------------------------------------------------------------------
__global__ void convert_w1_kernel(const float* __restrict__ w1,
                                  unsigned short* __restrict__ w1t_hi,
                                  unsigned short* __restrict__ w1t_lo) {
    int e = blockIdx.x;                       // 0..511
    int u = threadIdx.x + blockIdx.y * 256;   // 0..511
    float x = w1[(size_t)e * UDIM + u];
    unsigned ub = __float_as_uint(x);
    unsigned hb = ub & 0xffff0000u;
    float r = x - __uint_as_float(hb);
    w1t_hi[(size_t)u * KDIM + e] = (unsigned short)(hb >> 16);
    w1t_lo[(size_t)u * KDIM + e] = (unsigned short)(__float_as_uint(r) >> 16);
}

// ---------------------------------------------------------------------------
// Kernel A: h2 = hidden @ W2 + b2   [2048,512] fp32 vector GEMM (64x64 tile)
// ---------------------------------------------------------------------------
__global__ __launch_bounds__(256)
void h2_gemm_kernel(const float* __restrict__ hidden, const float* __restrict__ W2,
                    const float* __restrict__ b2, float* __restrict__ h2) {
    __shared__ float As[16][65];   // [k][m]
    __shared__ float Bs[16][68];   // [k][n], pad 4 keeps float4 alignment
    int tid = threadIdx.x;
    int bm = blockIdx.x, bn = blockIdx.y;     // grid (32, 8)
    int tx = tid & 15, ty = tid >> 4;
    float acc[4][4] = {};
    for (int k0 = 0; k0 < KDIM; k0 += 16) {
        {   // A tile 64x16
            int r = tid >> 2, c = (tid & 3) * 4;
            float4 v = *(const float4*)(hidden + (size_t)(bm * 64 + r) * KDIM + k0 + c);
            As[c + 0][r] = v.x; As[c + 1][r] = v.y; As[c + 2][r] = v.z; As[c + 3][r] = v.w;
        }
        {   // B tile 16x64
            int r = tid >> 4, c = (tid & 15) * 4;
            float4 v = *(const float4*)(W2 + (size_t)(k0 + r) * UDIM + bn * 64 + c);
            *(float4*)&Bs[r][c] = v;
        }
        __syncthreads();
        #pragma unroll
        for (int kk = 0; kk < 16; ++kk) {
            float a[4], b[4];
            #pragma unroll
            for (int i = 0; i < 4; ++i) a[i] = As[kk][ty * 4 + i];
            #pragma unroll
            for (int j = 0; j < 4; ++j) b[j] = Bs[kk][tx * 4 + j];
            #pragma unroll
            for (int i = 0; i < 4; ++i)
                #pragma unroll
                for (int j = 0; j < 4; ++j)
                    acc[i][j] += a[i] * b[j];
        }
        __syncthreads();
    }
    #pragma unroll
    for (int i = 0; i < 4; ++i)
        #pragma unroll
        for (int j = 0; j < 4; ++j) {
            int n = bn * 64 + tx * 4 + j;
            h2[(size_t)(bm * 64 + ty * 4 + i) * UDIM + n] = acc[i][j] + b2[n];
        }
}

// ---------------------------------------------------------------------------
// Kernel B: fused  h1 = feat@W1 (bf16x3 MFMA) ; partial scores via tanh·Wv
//   grid (4, 1024): bn = x (U tiles), bm = y (M tiles). block 256 = 4 waves.
//   spart[m][8] : 4 bn-blocks x 2 wn-waves partial dot(tanh(h1+h2+b1), Wv)
// ---------------------------------------------------------------------------
__global__ __launch_bounds__(256, 2)
void fused_score_kernel(const float* __restrict__ feat,
                        const unsigned short* __restrict__ w1t_hi,
                        const unsigned short* __restrict__ w1t_lo,
                        const float* __restrict__ h2,
                        const float* __restrict__ b1,
                        const float* __restrict__ wv,
                        float* __restrict__ spart) {
    __shared__ unsigned short Ah[128 * 32];
    __shared__ unsigned short Al[128 * 32];
    __shared__ unsigned short Bh[128 * 32];
    __shared__ unsigned short Bl[128 * 32];

    const int tid = threadIdx.x;
    const int bn = blockIdx.x;        // 0..3
    const int bm = blockIdx.y;        // 0..1023

    // staging coords
    const int a_kg = tid & 7;         // float4 slot within 32-k row
    const int a_r0 = tid >> 3;        // row 0..31 (+32 per pass)
    const int b_sl = tid & 3;         // 8-k slot
    const int b_r0 = tid >> 2;        // row 0..63 (+64 per pass)

    const float* aptr = feat + (size_t)(bm * 128 + a_r0) * KDIM + a_kg * 4;
    const unsigned short* bhp = w1t_hi + (size_t)(bn * 128 + b_r0) * KDIM + b_sl * 8;
    const unsigned short* blp = w1t_lo + (size_t)(bn * 128 + b_r0) * KDIM + b_sl * 8;

    float4 aR[4];
    int4 bhR[2], blR[2];
    #pragma unroll
    for (int p = 0; p < 4; ++p) aR[p] = *(const float4*)(aptr + (size_t)p * 32 * KDIM);
    #pragma unroll
    for (int p = 0; p < 2; ++p) {
        bhR[p] = *(const int4*)(bhp + (size_t)p * 64 * KDIM);
        blR[p] = *(const int4*)(blp + (size_t)p * 64 * KDIM);
    }

    // compute coords: wave (wm,wn) owns 64x64; 4x4 frags of 16x16
    const int l = tid & 63;
    const int wid = tid >> 6;
    const int wm = wid >> 1, wn = wid & 1;
    const int lane16 = l & 15, g = l >> 4;

    int aoff[4], boff[4];
    #pragma unroll
    for (int f = 0; f < 4; ++f) {
        int ar = wm * 64 + f * 16 + lane16;
        aoff[f] = ar * 32 + ((g ^ ((ar >> 1) & 3)) << 3);
        int br = wn * 64 + f * 16 + lane16;
        boff[f] = br * 32 + ((g ^ ((br >> 1) & 3)) << 3);
    }

    f32x4_t zero = {0.f, 0.f, 0.f, 0.f};
    f32x4_t acc[4][4];
    #pragma unroll
    for (int i = 0; i < 4; ++i)
        #pragma unroll
        for (int j = 0; j < 4; ++j) acc[i][j] = zero;

    auto stage = [&]() {
        #pragma unroll
        for (int p = 0; p < 4; ++p) {
            int row = a_r0 + p * 32;
            int idx = row * 32 + (((a_kg >> 1) ^ ((row >> 1) & 3)) << 3) + (a_kg & 1) * 4;
            float xs[4] = {aR[p].x, aR[p].y, aR[p].z, aR[p].w};
            u16x4_t h4, l4;
            #pragma unroll
            for (int c = 0; c < 4; ++c) {
                unsigned ub = __float_as_uint(xs[c]);
                unsigned hb = ub & 0xffff0000u;
                h4[c] = (unsigned short)(hb >> 16);
                float r = xs[c] - __uint_as_float(hb);
                l4[c] = (unsigned short)(__float_as_uint(r) >> 16);
            }
            *(u16x4_t*)(Ah + idx) = h4;
            *(u16x4_t*)(Al + idx) = l4;
        }
        #pragma unroll
        for (int p = 0; p < 2; ++p) {
            int row = b_r0 + p * 64;
            int idx = row * 32 + ((b_sl ^ ((row >> 1) & 3)) << 3);
            *(int4*)(Bh + idx) = bhR[p];
            *(int4*)(Bl + idx) = blR[p];
        }
    };

    #pragma unroll 1
    for (int ks = 0; ks < 16; ++ks) {
        stage();
        __syncthreads();
        if (ks < 15) {   // prefetch next K-step while computing this one
            int k0 = (ks + 1) * 32;
            #pragma unroll
            for (int p = 0; p < 4; ++p)
                aR[p] = *(const float4*)(aptr + k0 + (size_t)p * 32 * KDIM);
            #pragma unroll
            for (int p = 0; p < 2; ++p) {
                bhR[p] = *(const int4*)(bhp + k0 + (size_t)p * 64 * KDIM);
                blR[p] = *(const int4*)(blp + k0 + (size_t)p * 64 * KDIM);
            }
        }
        bf16x8_t bhf[4], blf[4];
        #pragma unroll
        for (int f = 0; f < 4; ++f) {
            bhf[f] = __builtin_bit_cast(bf16x8_t, *(const u16x8_t*)(Bh + boff[f]));
            blf[f] = __builtin_bit_cast(bf16x8_t, *(const u16x8_t*)(Bl + boff[f]));
        }
        #pragma unroll
        for (int i = 0; i < 4; ++i) {
            bf16x8_t ahf = __builtin_bit_cast(bf16x8_t, *(const u16x8_t*)(Ah + aoff[i]));
            bf16x8_t alf = __builtin_bit_cast(bf16x8_t, *(const u16x8_t*)(Al + aoff[i]));
            #pragma unroll
            for (int j = 0; j < 4; ++j) {
                acc[i][j] = __builtin_amdgcn_mfma_f32_16x16x32_bf16(ahf, bhf[j], acc[i][j], 0, 0, 0);
                acc[i][j] = __builtin_amdgcn_mfma_f32_16x16x32_bf16(ahf, blf[j], acc[i][j], 0, 0, 0);
                acc[i][j] = __builtin_amdgcn_mfma_f32_16x16x32_bf16(alf, bhf[j], acc[i][j], 0, 0, 0);
            }
        }
        __syncthreads();
    }

    // epilogue: s += tanh(h1 + h2 + b1) * Wv  over this wave's 64 u-columns
    const int brow = bm * 2 + wm;      // batch index (constant per wave)
    float b1v[4], wvv[4], h2v[4];
    #pragma unroll
    for (int j = 0; j < 4; ++j) {
        int ug = bn * 128 + wn * 64 + j * 16 + lane16;
        b1v[j] = b1[ug];
        wvv[j] = wv[ug];
        h2v[j] = h2[(size_t)brow * UDIM + ug];
    }
    #pragma unroll
    for (int i = 0; i < 4; ++i) {
        #pragma unroll
        for (int r = 0; r < 4; ++r) {
            float s = 0.f;
            #pragma unroll
            for (int j = 0; j < 4; ++j) {
                float h = acc[i][j][r] + b1v[j] + h2v[j];
                s += tanhf(h) * wvv[j];
            }
            s += __shfl_xor(s, 1);
            s += __shfl_xor(s, 2);
            s += __shfl_xor(s, 4);
            s += __shfl_xor(s, 8);
            if (lane16 == 0) {
                int mrow = bm * 128 + wm * 64 + i * 16 + g * 4 + r;   // C/D: row=(l>>4)*4+r
                spart[(size_t)mrow * 8 + bn * 2 + wn] = s;
            }
        }
    }
}

// ---------------------------------------------------------------------------
// Kernel C: softmax over S=64 + context = sum_s w_s * feat[b,s,:]
// ---------------------------------------------------------------------------
__global__ __launch_bounds__(256)
void softmax_context_kernel(const float* __restrict__ feat,
                            const float* __restrict__ spart,
                            const float* __restrict__ bv,
                            float* __restrict__ out) {
    int b = blockIdx.x;
    int tid = threadIdx.x;
    __shared__ float wsm[64];
    if (tid < 64) {
        const float* p = spart + (size_t)(b * 64 + tid) * 8;
        float s = ((p[0] + p[1]) + (p[2] + p[3])) + ((p[4] + p[5]) + (p[6] + p[7])) + bv[0];
        float m = s;
        #pragma unroll
        for (int off = 32; off; off >>= 1) m = fmaxf(m, __shfl_xor(m, off));
        float e = __expf(s - m);
        float sum = e;
        #pragma unroll
        for (int off = 32; off; off >>= 1) sum += __shfl_xor(sum, off);
        wsm[tid] = e / sum;
    }
    __syncthreads();
    float acc0 = 0.f, acc1 = 0.f;
    const float2* f2 = (const float2*)(feat + (size_t)b * 64 * KDIM);
    #pragma unroll 4
    for (int s = 0; s < 64; ++s) {
        float w = wsm[s];
        float2 v = f2[s * 256 + tid];
        acc0 += w * v.x;
        acc1 += w * v.y;
    }
    ((float2*)out)[(size_t)b * 256 + tid] = make_float2(acc0, acc1);
}

// ---------------------------------------------------------------------------
extern "C" void kernel_launch(void* const* d_in, const int* in_sizes, int n_in,
                              void* d_out, int out_size, void* d_ws, size_t ws_size,
                              hipStream_t stream) {
    (void)in_sizes; (void)n_in; (void)out_size; (void)ws_size;
    const float* feat   = (const float*)d_in[0];   // [2048,64,512]
    const float* hidden = (const float*)d_in[1];   // [2048,512]
    const float* W1     = (const float*)d_in[2];   // [512,512]
    const float* b1     = (const float*)d_in[3];   // [512]
    const float* W2     = (const float*)d_in[4];   // [512,512]
    const float* b2     = (const float*)d_in[5];   // [512]
    const float* Wv     = (const float*)d_in[6];   // [512,1]
    const float* bv     = (const float*)d_in[7];   // [1]
    float* out = (float*)d_out;                    // [2048,512]

    char* ws = (char*)d_ws;
    unsigned short* w1t_hi = (unsigned short*)(ws);             // 512 KB
    unsigned short* w1t_lo = (unsigned short*)(ws + 524288);    // 512 KB
    float* h2    = (float*)(ws + 1048576);                      // 4 MB
    float* spart = (float*)(ws + 5242880);                      // 4 MB [131072][8]

    convert_w1_kernel<<<dim3(512, 2), dim3(256), 0, stream>>>(W1, w1t_hi, w1t_lo);
    h2_gemm_kernel<<<dim3(32, 8), dim3(256), 0, stream>>>(hidden, W2, b2, h2);
    fused_score_kernel<<<dim3(4, 1024), dim3(256), 0, stream>>>(feat, w1t_hi, w1t_lo,
                                                                h2, b1, Wv, spart);
    softmax_context_kernel<<<dim3(2048), dim3(256), 0, stream>>>(feat, spart, bv, out);
}

// Round 2
// 184.163 us; speedup vs baseline: 2.9584x; 2.9584x over previous
//
#include <hip/hip_runtime.h>

typedef _Float16 f16x8 __attribute__((ext_vector_type(8)));
typedef float f32x4 __attribute__((ext_vector_type(4)));

#define KDIM 512
#define UDIM 512

__device__ inline void gload_lds16(const void* gsrc, void* ldst) {
    __builtin_amdgcn_global_load_lds(
        (const unsigned int __attribute__((address_space(1)))*)gsrc,
        (unsigned int __attribute__((address_space(3)))*)ldst,
        16, 0, 0);
}

// ---------------------------------------------------------------------------
// Kernel 0: W1 [E,U] f32 -> fp16 swizzled LDS-image, [16 ktiles][32768 B].
// Image byte layout per ktile: u*64 + ((kslot ^ ((u>>1)&3))<<4) + b
// so a linear global_load_lds copy lands as the swizzled Bs the frags read.
// ---------------------------------------------------------------------------
__global__ void convert_w1_kernel(const float* __restrict__ w1,
                                  unsigned short* __restrict__ img) {
    int k = blockIdx.x;                       // e index 0..511
    int u = threadIdx.x + blockIdx.y * 256;   // 0..511
    float x = w1[(size_t)k * UDIM + u];
    _Float16 h = (_Float16)x;
    int ktile = k >> 5, kk = k & 31;
    int kslot = kk >> 3, b = kk & 7;
    img[(size_t)ktile * 16384 + u * 32 + ((kslot ^ ((u >> 1) & 3)) << 3) + b] =
        __builtin_bit_cast(unsigned short, h);
}

// ---------------------------------------------------------------------------
// Kernel A: h2 = hidden @ W2 + b2   [2048,512] fp32 vector GEMM (64x64 tile)
// ---------------------------------------------------------------------------
__global__ __launch_bounds__(256)
void h2_gemm_kernel(const float* __restrict__ hidden, const float* __restrict__ W2,
                    const float* __restrict__ b2, float* __restrict__ h2) {
    __shared__ float As[16][65];
    __shared__ float Bs[16][68];
    int tid = threadIdx.x;
    int bm = blockIdx.x, bn = blockIdx.y;     // grid (32, 8)
    int tx = tid & 15, ty = tid >> 4;
    float acc[4][4] = {};
    for (int k0 = 0; k0 < KDIM; k0 += 16) {
        {
            int r = tid >> 2, c = (tid & 3) * 4;
            float4 v = *(const float4*)(hidden + (size_t)(bm * 64 + r) * KDIM + k0 + c);
            As[c + 0][r] = v.x; As[c + 1][r] = v.y; As[c + 2][r] = v.z; As[c + 3][r] = v.w;
        }
        {
            int r = tid >> 4, c = (tid & 15) * 4;
            float4 v = *(const float4*)(W2 + (size_t)(k0 + r) * UDIM + bn * 64 + c);
            *(float4*)&Bs[r][c] = v;
        }
        __syncthreads();
        #pragma unroll
        for (int kk = 0; kk < 16; ++kk) {
            float a[4], b[4];
            #pragma unroll
            for (int i = 0; i < 4; ++i) a[i] = As[kk][ty * 4 + i];
            #pragma unroll
            for (int j = 0; j < 4; ++j) b[j] = Bs[kk][tx * 4 + j];
            #pragma unroll
            for (int i = 0; i < 4; ++i)
                #pragma unroll
                for (int j = 0; j < 4; ++j)
                    acc[i][j] += a[i] * b[j];
        }
        __syncthreads();
    }
    #pragma unroll
    for (int i = 0; i < 4; ++i)
        #pragma unroll
        for (int j = 0; j < 4; ++j) {
            int n = bn * 64 + tx * 4 + j;
            h2[(size_t)(bm * 64 + ty * 4 + i) * UDIM + n] = acc[i][j] + b2[n];
        }
}

// ---------------------------------------------------------------------------
// Kernel B (fused): per block: 128 feat rows (2 batches) x full U=512.
//   h1 = feat@W1 (fp16 MFMA) -> tanh(.+b1+h2)·Wv -> scores -> softmax(S=64)
//   -> context = sum_s w_s * feat  — all in one kernel.
//   8 waves (2m x 4n), wave tile 64x128, BK=32, double-buffered LDS,
//   B via global_load_lds from pre-swizzled image, A reg-staged fp32->fp16.
// ---------------------------------------------------------------------------
__global__ __launch_bounds__(512, 2)
void fused_all_kernel(const float* __restrict__ feat,
                      const unsigned short* __restrict__ w1img,
                      const float* __restrict__ h2,
                      const float* __restrict__ b1,
                      const float* __restrict__ wv,
                      float* __restrict__ out) {
    __shared__ unsigned short As[2 * 4096];    // 2 x 128x32 fp16 = 16 KB
    __shared__ unsigned short Bs[2 * 16384];   // 2 x 512x32 fp16 = 64 KB
    __shared__ float spl[128 * 4];
    __shared__ float wsm[128];

    const int tid = threadIdx.x;
    const int bm = blockIdx.x;            // 0..1023
    const int lane = tid & 63;
    const int wid = tid >> 6;             // 0..7
    const int wm = wid >> 2;              // 0..1 (64 M-rows each)
    const int wn = wid & 3;               // 0..3 (128 U-cols each)
    const int lane16 = lane & 15, g = lane >> 4;

    // A staging coords: thread -> (row, kslot of 8 floats)
    const int s_row = tid >> 2;           // 0..127
    const int s_ks  = tid & 3;
    const float* aptr = feat + (size_t)(bm * 128 + s_row) * KDIM + s_ks * 8;
    const int a_widx = s_row * 32 + ((s_ks ^ ((s_row >> 1) & 3)) << 3); // u16 units

    // fragment offsets (u16 units)
    int aoff[4], boff[8];
    #pragma unroll
    for (int i = 0; i < 4; ++i) {
        int r = wm * 64 + i * 16 + lane16;
        aoff[i] = r * 32 + ((g ^ ((r >> 1) & 3)) << 3);
    }
    #pragma unroll
    for (int j = 0; j < 8; ++j) {
        int u = wn * 128 + j * 16 + lane16;
        boff[j] = u * 32 + ((g ^ ((u >> 1) & 3)) << 3);
    }

    // epilogue constants (h2 already includes b2)
    const int brow = bm * 2 + wm;
    float hhv[8], wvv[8];
    #pragma unroll
    for (int j = 0; j < 8; ++j) {
        int u = wn * 128 + j * 16 + lane16;
        hhv[j] = b1[u] + h2[(size_t)brow * UDIM + u];
        wvv[j] = wv[u];
    }

    f32x4 acc[4][8];
    #pragma unroll
    for (int i = 0; i < 4; ++i)
        #pragma unroll
        for (int j = 0; j < 8; ++j) acc[i][j] = (f32x4){0.f, 0.f, 0.f, 0.f};

    const char* bsrc = (const char*)w1img;
    const int bq = wid * 1024 + lane * 16;   // byte offset within an 8KB issue

    // ---- prologue: stage tile 0, prefetch A(1) ----
    float4 a0 = *(const float4*)(aptr);
    float4 a1 = *(const float4*)(aptr + 4);
    {
        f16x8 h8;
        h8[0] = (_Float16)a0.x; h8[1] = (_Float16)a0.y; h8[2] = (_Float16)a0.z; h8[3] = (_Float16)a0.w;
        h8[4] = (_Float16)a1.x; h8[5] = (_Float16)a1.y; h8[6] = (_Float16)a1.z; h8[7] = (_Float16)a1.w;
        *(f16x8*)(As + a_widx) = h8;
    }
    #pragma unroll
    for (int q = 0; q < 4; ++q)
        gload_lds16(bsrc + q * 8192 + bq, (char*)Bs + q * 8192 + bq);
    a0 = *(const float4*)(aptr + 32);
    a1 = *(const float4*)(aptr + 36);
    __syncthreads();

    // ---- main loop: one barrier per k-step ----
    #pragma unroll 1
    for (int t = 0; t < 16; ++t) {
        const int cur = t & 1;
        const unsigned short* Ac = As + cur * 4096;
        const unsigned short* Bc = Bs + cur * 16384;
        if (t < 15) {
            const int nxt = cur ^ 1;
            const char* bsp = bsrc + (size_t)(t + 1) * 32768;
            char* bld = (char*)Bs + nxt * 32768;
            #pragma unroll
            for (int q = 0; q < 4; ++q)
                gload_lds16(bsp + q * 8192 + bq, bld + q * 8192 + bq);
            f16x8 h8;
            h8[0] = (_Float16)a0.x; h8[1] = (_Float16)a0.y; h8[2] = (_Float16)a0.z; h8[3] = (_Float16)a0.w;
            h8[4] = (_Float16)a1.x; h8[5] = (_Float16)a1.y; h8[6] = (_Float16)a1.z; h8[7] = (_Float16)a1.w;
            *(f16x8*)(As + nxt * 4096 + a_widx) = h8;
        }
        if (t < 14) {
            a0 = *(const float4*)(aptr + (t + 2) * 32);
            a1 = *(const float4*)(aptr + (t + 2) * 32 + 4);
        }
        f16x8 bf[8];
        #pragma unroll
        for (int j = 0; j < 8; ++j) bf[j] = *(const f16x8*)(Bc + boff[j]);
        #pragma unroll
        for (int i = 0; i < 4; ++i) {
            f16x8 af = *(const f16x8*)(Ac + aoff[i]);
            #pragma unroll
            for (int j = 0; j < 8; ++j)
                acc[i][j] = __builtin_amdgcn_mfma_f32_16x16x32_f16(af, bf[j], acc[i][j], 0, 0, 0);
        }
        __syncthreads();
    }

    // ---- epilogue 1: scores (tanh + dot with Wv), per-wave partials ----
    #pragma unroll
    for (int i = 0; i < 4; ++i) {
        #pragma unroll
        for (int r = 0; r < 4; ++r) {
            float s = 0.f;
            #pragma unroll
            for (int j = 0; j < 8; ++j) {
                float h = acc[i][j][r] + hhv[j];
                float ex = __expf(2.f * h);                       // tanh via exp
                float th = 1.f - 2.f * __builtin_amdgcn_rcpf(ex + 1.f);
                s += th * wvv[j];
            }
            s += __shfl_xor(s, 1); s += __shfl_xor(s, 2);
            s += __shfl_xor(s, 4); s += __shfl_xor(s, 8);
            if (lane16 == 0)
                spl[(wm * 64 + i * 16 + g * 4 + r) * 4 + wn] = s;
        }
    }
    __syncthreads();

    // ---- epilogue 2: softmax over S=64 per batch (bv shift is a no-op) ----
    if (tid < 128) {
        float s = (spl[tid * 4 + 0] + spl[tid * 4 + 1]) +
                  (spl[tid * 4 + 2] + spl[tid * 4 + 3]);
        float m = s;
        #pragma unroll
        for (int off = 32; off; off >>= 1) m = fmaxf(m, __shfl_xor(m, off));
        float e = __expf(s - m);
        float sum = e;
        #pragma unroll
        for (int off = 32; off; off >>= 1) sum += __shfl_xor(sum, off);
        wsm[tid] = e / sum;
    }
    __syncthreads();

    // ---- epilogue 3: context = sum_s w_s * feat (rows are L2-hot) ----
    {
        const int b = tid >> 8, c = tid & 255;
        const float2* f2 = (const float2*)(feat + (size_t)(bm * 128 + b * 64) * KDIM);
        float ax = 0.f, ay = 0.f;
        #pragma unroll 4
        for (int s = 0; s < 64; ++s) {
            float w = wsm[b * 64 + s];
            float2 v = f2[s * 256 + c];
            ax += w * v.x; ay += w * v.y;
        }
        ((float2*)out)[(size_t)(bm * 2 + b) * 256 + c] = make_float2(ax, ay);
    }
}

// ---------------------------------------------------------------------------
extern "C" void kernel_launch(void* const* d_in, const int* in_sizes, int n_in,
                              void* d_out, int out_size, void* d_ws, size_t ws_size,
                              hipStream_t stream) {
    (void)in_sizes; (void)n_in; (void)out_size; (void)ws_size;
    const float* feat   = (const float*)d_in[0];   // [2048,64,512]
    const float* hidden = (const float*)d_in[1];   // [2048,512]
    const float* W1     = (const float*)d_in[2];   // [512,512]
    const float* b1     = (const float*)d_in[3];   // [512]
    const float* W2     = (const float*)d_in[4];   // [512,512]
    const float* b2     = (const float*)d_in[5];   // [512]
    const float* Wv     = (const float*)d_in[6];   // [512,1]
    // d_in[7] = bv: softmax is shift-invariant, unused.
    float* out = (float*)d_out;                    // [2048,512]

    char* ws = (char*)d_ws;
    unsigned short* w1img = (unsigned short*)(ws);        // 512 KB
    float* h2 = (float*)(ws + 524288);                    // 4 MB

    convert_w1_kernel<<<dim3(512, 2), dim3(256), 0, stream>>>(W1, w1img);
    h2_gemm_kernel<<<dim3(32, 8), dim3(256), 0, stream>>>(hidden, W2, b2, h2);
    fused_all_kernel<<<dim3(1024), dim3(512), 0, stream>>>(feat, w1img, h2, b1, Wv, out);
}

// Round 3
// 177.639 us; speedup vs baseline: 3.0670x; 1.0367x over previous
//
#include <hip/hip_runtime.h>

typedef _Float16 f16x8 __attribute__((ext_vector_type(8)));
typedef float f32x4 __attribute__((ext_vector_type(4)));

#define KDIM 512
#define UDIM 512

__device__ __forceinline__ void gload_lds16(const void* gsrc, void* ldst) {
    __builtin_amdgcn_global_load_lds(
        (const unsigned int __attribute__((address_space(1)))*)gsrc,
        (unsigned int __attribute__((address_space(3)))*)ldst,
        16, 0, 0);
}

__device__ __forceinline__ void cvt_store_a(unsigned short* dst, float4 a0, float4 a1) {
    f16x8 h8;
    h8[0] = (_Float16)a0.x; h8[1] = (_Float16)a0.y;
    h8[2] = (_Float16)a0.z; h8[3] = (_Float16)a0.w;
    h8[4] = (_Float16)a1.x; h8[5] = (_Float16)a1.y;
    h8[6] = (_Float16)a1.z; h8[7] = (_Float16)a1.w;
    *(f16x8*)dst = h8;
}

// ---------------------------------------------------------------------------
// Shared 64x512 fp16-MFMA GEMM tile, counted-vmcnt pipeline (T3/T4).
// 256 threads = 4 waves; wave `wid` owns cols [wid*128, wid*128+128).
// acc[i][j][r] = C[i*16 + g*4 + r][wid*128 + j*16 + lane16].
// LDS: As = 2 x 64x32 fp16 (8 KB), Bs = 2 x 512x32 fp16 (64 KB).
// B comes from a pre-swizzled fp16 image (16 ktiles x 32 KB, linear copy).
// vmcnt ledger per iter: issue 8 gload_lds(B) -> vmcnt(8) waits prev A regs
// -> ds_write A -> issue 2 A loads -> MFMA -> vmcnt(2) waits own B -> barrier.
// ---------------------------------------------------------------------------
__device__ __forceinline__ void mfma_gemm_64x512(
    const float* __restrict__ aSrc, const unsigned short* __restrict__ bImg,
    unsigned short* As, unsigned short* Bs, int tid, f32x4 acc[4][8])
{
    const int lane = tid & 63, wid = tid >> 6;
    const int lane16 = lane & 15, g = lane >> 4;
    const int s_row = tid >> 2, s_ks = tid & 3;
    const float* aptr = aSrc + (size_t)s_row * KDIM + s_ks * 8;
    const int a_widx = s_row * 32 + ((s_ks ^ ((s_row >> 1) & 3)) << 3);

    int aoff[4], boff[8];
    #pragma unroll
    for (int i = 0; i < 4; ++i) {
        int r = i * 16 + lane16;
        aoff[i] = r * 32 + ((g ^ ((r >> 1) & 3)) << 3);
    }
    #pragma unroll
    for (int j = 0; j < 8; ++j) {
        int u = wid * 128 + j * 16 + lane16;
        boff[j] = u * 32 + ((g ^ ((u >> 1) & 3)) << 3);
    }
    #pragma unroll
    for (int i = 0; i < 4; ++i)
        #pragma unroll
        for (int j = 0; j < 8; ++j) acc[i][j] = (f32x4){0.f, 0.f, 0.f, 0.f};

    const char* bsrc = (const char*)bImg;
    const int bq = tid * 16;                       // byte offset in 4 KB chunk

    // ---- prologue: tile 0 staged, A(1) in flight, queue = 2 ----
    #pragma unroll
    for (int q = 0; q < 8; ++q)
        gload_lds16(bsrc + q * 4096 + bq, (char*)Bs + q * 4096 + bq);
    float4 a0 = *(const float4*)(aptr);
    float4 a1 = *(const float4*)(aptr + 4);
    asm volatile("s_waitcnt vmcnt(0)" ::: "memory");
    cvt_store_a(As + a_widx, a0, a1);
    a0 = *(const float4*)(aptr + 32);
    a1 = *(const float4*)(aptr + 36);
    asm volatile("s_waitcnt lgkmcnt(0)" ::: "memory");
    __builtin_amdgcn_s_barrier();
    asm volatile("" ::: "memory");

    #pragma unroll 1
    for (int t = 0; t < 16; ++t) {
        const int cur = t & 1, nxt = cur ^ 1;
        const unsigned short* Ac = As + cur * 2048;
        const unsigned short* Bc = Bs + cur * 16384;
        if (t < 15) {
            const char* bsp = bsrc + (size_t)(t + 1) * 32768;
            char* bld = (char*)Bs + nxt * 32768;
            #pragma unroll
            for (int q = 0; q < 8; ++q)
                gload_lds16(bsp + q * 4096 + bq, bld + q * 4096 + bq);
            asm volatile("s_waitcnt vmcnt(8)" ::: "memory");  // A(t+1) regs ready
            cvt_store_a(As + nxt * 2048 + a_widx, a0, a1);
        }
        if (t < 14) {
            a0 = *(const float4*)(aptr + (t + 2) * 32);
            a1 = *(const float4*)(aptr + (t + 2) * 32 + 4);
        }
        f16x8 bf[8];
        #pragma unroll
        for (int j = 0; j < 8; ++j) bf[j] = *(const f16x8*)(Bc + boff[j]);
        #pragma unroll
        for (int i = 0; i < 4; ++i) {
            f16x8 af = *(const f16x8*)(Ac + aoff[i]);
            #pragma unroll
            for (int j = 0; j < 8; ++j)
                acc[i][j] = __builtin_amdgcn_mfma_f32_16x16x32_f16(af, bf[j], acc[i][j], 0, 0, 0);
        }
        if (t < 14)       { asm volatile("s_waitcnt vmcnt(2)" ::: "memory"); }
        else if (t == 14) { asm volatile("s_waitcnt vmcnt(0)" ::: "memory"); }
        if (t < 15) {
            asm volatile("s_waitcnt lgkmcnt(0)" ::: "memory");
            __builtin_amdgcn_s_barrier();
            asm volatile("" ::: "memory");
        }
    }
}

// ---------------------------------------------------------------------------
// Kernel 0: W1,W2 [K,U] f32 -> fp16 pre-swizzled images [16 ktiles][32 KB].
// Image (u16 units): ktile*16384 + u*32 + ((kslot ^ ((u>>1)&3))<<3) + (k&7)
// ---------------------------------------------------------------------------
__global__ void convert_w_kernel(const float* __restrict__ w1,
                                 const float* __restrict__ w2,
                                 unsigned short* __restrict__ w1img,
                                 unsigned short* __restrict__ w2img) {
    int k = blockIdx.x;                       // 0..511 (contraction dim)
    int u = threadIdx.x + blockIdx.y * 256;   // 0..511
    int ktile = k >> 5, kk = k & 31;
    size_t idx = (size_t)ktile * 16384 + u * 32 +
                 (((kk >> 3) ^ ((u >> 1) & 3)) << 3) + (kk & 7);
    _Float16 h1 = (_Float16)w1[(size_t)k * UDIM + u];
    _Float16 h2 = (_Float16)w2[(size_t)k * UDIM + u];
    w1img[idx] = __builtin_bit_cast(unsigned short, h1);
    w2img[idx] = __builtin_bit_cast(unsigned short, h2);
}

// ---------------------------------------------------------------------------
// Kernel A: h2 = hidden @ W2 + b2 via the shared fp16 MFMA tile (32 blocks)
// ---------------------------------------------------------------------------
__global__ __launch_bounds__(256, 2)
void h2_gemm_f16_kernel(const float* __restrict__ hidden,
                        const unsigned short* __restrict__ w2img,
                        const float* __restrict__ b2,
                        float* __restrict__ h2) {
    __shared__ unsigned short As[2 * 2048];
    __shared__ unsigned short Bs[2 * 16384];
    const int tid = threadIdx.x, bm = blockIdx.x;
    const int lane = tid & 63, wid = tid >> 6;
    const int lane16 = lane & 15, g = lane >> 4;

    f32x4 acc[4][8];
    mfma_gemm_64x512(hidden + (size_t)bm * 64 * KDIM, w2img, As, Bs, tid, acc);

    #pragma unroll
    for (int j = 0; j < 8; ++j) {
        int col = wid * 128 + j * 16 + lane16;
        float bb = b2[col];
        #pragma unroll
        for (int i = 0; i < 4; ++i)
            #pragma unroll
            for (int r = 0; r < 4; ++r) {
                int row = bm * 64 + i * 16 + g * 4 + r;
                h2[(size_t)row * UDIM + col] = acc[i][j][r] + bb;
            }
    }
}

// ---------------------------------------------------------------------------
// Kernel B (fused): block = 1 batch (64 feat rows) x full U=512.
//   h1 = feat@W1 (fp16 MFMA, pipelined) -> tanh(.+b1+h2)·Wv -> softmax(S=64)
//   -> context = sum_s w_s * feat[b,s,:]   (feat rows L2-hot)
// ---------------------------------------------------------------------------
__global__ __launch_bounds__(256, 2)
void fused_all_kernel(const float* __restrict__ feat,
                      const unsigned short* __restrict__ w1img,
                      const float* __restrict__ h2,
                      const float* __restrict__ b1,
                      const float* __restrict__ wv,
                      float* __restrict__ out) {
    __shared__ unsigned short As[2 * 2048];
    __shared__ unsigned short Bs[2 * 16384];
    __shared__ float spl[64 * 4];
    __shared__ float wsm[64];

    const int tid = threadIdx.x;
    const int bm = blockIdx.x;                // batch index 0..2047
    const int lane = tid & 63, wid = tid >> 6;
    const int lane16 = lane & 15, g = lane >> 4;

    // epilogue constants — issued BEFORE the pipeline's vmcnt(0) so the
    // counted-vmcnt ledger inside mfma_gemm_64x512 stays exact.
    float hhv[8], wvv[8];
    #pragma unroll
    for (int j = 0; j < 8; ++j) {
        int u = wid * 128 + j * 16 + lane16;
        hhv[j] = b1[u] + h2[(size_t)bm * UDIM + u];
        wvv[j] = wv[u];
    }

    f32x4 acc[4][8];
    mfma_gemm_64x512(feat + (size_t)bm * 64 * KDIM, w1img, As, Bs, tid, acc);

    // ---- scores: tanh + dot(Wv) over this wave's 128 cols ----
    #pragma unroll
    for (int i = 0; i < 4; ++i) {
        #pragma unroll
        for (int r = 0; r < 4; ++r) {
            float s = 0.f;
            #pragma unroll
            for (int j = 0; j < 8; ++j) {
                float h = acc[i][j][r] + hhv[j];
                float ex = __expf(2.f * h);
                float th = 1.f - 2.f * __builtin_amdgcn_rcpf(ex + 1.f);
                s += th * wvv[j];
            }
            s += __shfl_xor(s, 1); s += __shfl_xor(s, 2);
            s += __shfl_xor(s, 4); s += __shfl_xor(s, 8);
            if (lane16 == 0)
                spl[(i * 16 + g * 4 + r) * 4 + wid] = s;
        }
    }
    __syncthreads();

    // ---- softmax over S=64 (bv shift is a softmax no-op) ----
    if (tid < 64) {
        float s = (spl[tid * 4 + 0] + spl[tid * 4 + 1]) +
                  (spl[tid * 4 + 2] + spl[tid * 4 + 3]);
        float m = s;
        #pragma unroll
        for (int off = 32; off; off >>= 1) m = fmaxf(m, __shfl_xor(m, off));
        float e = __expf(s - m);
        float sum = e;
        #pragma unroll
        for (int off = 32; off; off >>= 1) sum += __shfl_xor(sum, off);
        wsm[tid] = e / sum;
    }
    __syncthreads();

    // ---- context: 256 threads x float2 over 512 cols, 64 seq steps ----
    {
        const float2* f2 = (const float2*)(feat + (size_t)bm * 64 * KDIM);
        float ax = 0.f, ay = 0.f;
        #pragma unroll 8
        for (int s = 0; s < 64; ++s) {
            float w = wsm[s];
            float2 v = f2[s * 256 + tid];
            ax += w * v.x; ay += w * v.y;
        }
        ((float2*)out)[(size_t)bm * 256 + tid] = make_float2(ax, ay);
    }
}

// ---------------------------------------------------------------------------
extern "C" void kernel_launch(void* const* d_in, const int* in_sizes, int n_in,
                              void* d_out, int out_size, void* d_ws, size_t ws_size,
                              hipStream_t stream) {
    (void)in_sizes; (void)n_in; (void)out_size; (void)ws_size;
    const float* feat   = (const float*)d_in[0];   // [2048,64,512]
    const float* hidden = (const float*)d_in[1];   // [2048,512]
    const float* W1     = (const float*)d_in[2];   // [512,512]
    const float* b1     = (const float*)d_in[3];   // [512]
    const float* W2     = (const float*)d_in[4];   // [512,512]
    const float* b2     = (const float*)d_in[5];   // [512]
    const float* Wv     = (const float*)d_in[6];   // [512,1]
    // d_in[7] = bv: softmax shift-invariant, unused.
    float* out = (float*)d_out;                    // [2048,512]

    char* ws = (char*)d_ws;
    unsigned short* w1img = (unsigned short*)(ws);            // 512 KB
    unsigned short* w2img = (unsigned short*)(ws + 524288);   // 512 KB
    float* h2 = (float*)(ws + 1048576);                       // 4 MB

    convert_w_kernel<<<dim3(512, 2), dim3(256), 0, stream>>>(W1, W2, w1img, w2img);
    h2_gemm_f16_kernel<<<dim3(32), dim3(256), 0, stream>>>(hidden, w2img, b2, h2);
    fused_all_kernel<<<dim3(2048), dim3(256), 0, stream>>>(feat, w1img, h2, b1, Wv, out);
}

// Round 4
// 155.102 us; speedup vs baseline: 3.5127x; 1.1453x over previous
//
#include <hip/hip_runtime.h>

typedef _Float16 f16x8 __attribute__((ext_vector_type(8)));
typedef float f32x4 __attribute__((ext_vector_type(4)));

#define KDIM 512
#define UDIM 512

#define VMWAIT(N) asm volatile("s_waitcnt vmcnt(" #N ")" ::: "memory")
#define LGKM0()   asm volatile("s_waitcnt lgkmcnt(0)" ::: "memory")
#define FENCE()   asm volatile("" ::: "memory")
#define BAR()     do { __builtin_amdgcn_s_barrier(); FENCE(); } while (0)

__device__ __forceinline__ void cvt_store_a(unsigned short* dst, float4 a0, float4 a1) {
    f16x8 h8;
    h8[0] = (_Float16)a0.x; h8[1] = (_Float16)a0.y;
    h8[2] = (_Float16)a0.z; h8[3] = (_Float16)a0.w;
    h8[4] = (_Float16)a1.x; h8[5] = (_Float16)a1.y;
    h8[6] = (_Float16)a1.z; h8[7] = (_Float16)a1.w;
    *(f16x8*)dst = h8;
}

// ---------------------------------------------------------------------------
// Kernel 0: W [K,U] f32 -> fp16 image, plain layout [ktile][u][32] u16.
// Write-coalesced: u per block, k per thread (32 lanes -> one 64B chunk).
// ---------------------------------------------------------------------------
__global__ void convert_w_kernel(const float* __restrict__ w1,
                                 const float* __restrict__ w2,
                                 unsigned short* __restrict__ w1img,
                                 unsigned short* __restrict__ w2img) {
    int u = blockIdx.x;                           // 0..511
    int k = threadIdx.x + blockIdx.y * 256;       // 0..511
    size_t idx = (size_t)(k >> 5) * 16384 + (size_t)u * 32 + (k & 31);
    _Float16 h1 = (_Float16)w1[(size_t)k * UDIM + u];
    _Float16 h2 = (_Float16)w2[(size_t)k * UDIM + u];
    w1img[idx] = __builtin_bit_cast(unsigned short, h1);
    w2img[idx] = __builtin_bit_cast(unsigned short, h2);
}

// ---------------------------------------------------------------------------
// Pipelined 64x512 fp16-MFMA GEMM core. 256 thr = 4 waves; wave wid owns
// cols [wid*128, +128). A (fp32, HBM) reg-staged->cvt->LDS dbuf (2x4KB).
// B read global->registers from L2-hot fp16 image, 2-deep double buffer.
// Ledger: each step issues {A(t+3) x2, B(t+2) x8}; one vmcnt(10)/step.
// ---------------------------------------------------------------------------
__device__ __forceinline__ void gemm_pipe_64x512(
    const float* __restrict__ aSrc, const char* __restrict__ bImg,
    unsigned short* As, f32x4 acc[4][8])
{
    const int tid = threadIdx.x;
    const int lane = tid & 63, wid = tid >> 6;
    const int lane16 = lane & 15, g = lane >> 4;

    // A staging coords: 4 threads per row, 8 floats each (BK=32)
    const int s_row = tid >> 2, s_ks = tid & 3;
    const float* aptr = aSrc + (size_t)s_row * KDIM + s_ks * 8;
    const int a_widx = s_row * 32 + ((s_ks ^ ((s_row >> 1) & 3)) << 3);

    int aoff[4];
    #pragma unroll
    for (int i = 0; i < 4; ++i) {
        int r = i * 16 + lane16;
        aoff[i] = r * 32 + ((g ^ ((r >> 1) & 3)) << 3);
    }
    // B frag byte base: u-row = wid*128 + j*16 + lane16, k-group g
    const char* bbase = bImg + (size_t)(wid * 128 + lane16) * 64 + g * 16;

    #pragma unroll
    for (int i = 0; i < 4; ++i)
        #pragma unroll
        for (int j = 0; j < 8; ++j) acc[i][j] = (f32x4){0.f, 0.f, 0.f, 0.f};

    f16x8 brA[8], brB[8];
    // ---- prologue: FIFO = [B0 x8, B1 x8, A0 x2, A1 x2] ----
    #pragma unroll
    for (int j = 0; j < 8; ++j) brA[j] = *(const f16x8*)(bbase + j * 1024);
    FENCE();
    #pragma unroll
    for (int j = 0; j < 8; ++j) brB[j] = *(const f16x8*)(bbase + 32768 + j * 1024);
    FENCE();
    float4 aE0 = *(const float4*)(aptr);
    float4 aE1 = *(const float4*)(aptr + 4);
    FENCE();
    float4 aO0 = *(const float4*)(aptr + 32);
    float4 aO1 = *(const float4*)(aptr + 36);
    FENCE();
    VMWAIT(2);                                  // A(0),B(0),B(1) done; A(1) in flight
    cvt_store_a(As + a_widx, aE0, aE1);         // buf0 = A(0)
    aE0 = *(const float4*)(aptr + 64);          // issue A(2)
    aE1 = *(const float4*)(aptr + 68);
    FENCE();
    LGKM0(); BAR();

    // step t: wait done; cvt AR -> buf(cur^1); issue A(t+3)->AR; read buf(cur),
    // MFMA with BR; issue B(t+2)->BR; barrier.
#define PSTEP(T, CUR, BR, AC0, AC1, DO_CVT, DO_A, DO_B, DO_BAR) do {            \
    if (DO_CVT) cvt_store_a(As + ((CUR) ^ 1) * 2048 + a_widx, AC0, AC1);         \
    if (DO_A) { AC0 = *(const float4*)(aptr + ((T) + 3) * 32);                   \
                AC1 = *(const float4*)(aptr + ((T) + 3) * 32 + 4); }             \
    FENCE();                                                                     \
    __builtin_amdgcn_s_setprio(1);                                               \
    _Pragma("unroll")                                                            \
    for (int i_ = 0; i_ < 4; ++i_) {                                             \
        f16x8 af_ = *(const f16x8*)(As + (CUR) * 2048 + aoff[i_]);               \
        _Pragma("unroll")                                                        \
        for (int j_ = 0; j_ < 8; ++j_)                                           \
            acc[i_][j_] = __builtin_amdgcn_mfma_f32_16x16x32_f16(                \
                af_, BR[j_], acc[i_][j_], 0, 0, 0);                              \
    }                                                                            \
    __builtin_amdgcn_s_setprio(0);                                               \
    if (DO_B) { _Pragma("unroll")                                                \
        for (int j_ = 0; j_ < 8; ++j_)                                           \
            BR[j_] = *(const f16x8*)(bbase + ((T) + 2) * 32768 + j_ * 1024); }   \
    if (DO_BAR) { LGKM0(); BAR(); }                                              \
} while (0)

    VMWAIT(2);  PSTEP(0, 0, brA, aO0, aO1, true, true, true, true);
    #pragma unroll 1
    for (int i = 0; i < 6; ++i) {
        const int t = 2 * i + 1;
        VMWAIT(10); PSTEP(t,     1, brB, aE0, aE1, true, true, true, true);
        VMWAIT(10); PSTEP(t + 1, 0, brA, aO0, aO1, true, true, true, true);
    }
    VMWAIT(10); PSTEP(13, 1, brB, aE0, aE1, true,  false, true,  true);
    VMWAIT(8);  PSTEP(14, 0, brA, aO0, aO1, true,  false, false, true);
    VMWAIT(0);  PSTEP(15, 1, brB, aE0, aE1, false, false, false, false);
#undef PSTEP
}

// ---------------------------------------------------------------------------
// Kernel A: h2 = hidden @ W2 + b2  (32 blocks, same pipelined core)
// ---------------------------------------------------------------------------
__global__ __launch_bounds__(256, 2)
void h2_gemm_f16_kernel(const float* __restrict__ hidden,
                        const char* __restrict__ w2img,
                        const float* __restrict__ b2,
                        float* __restrict__ h2) {
    __shared__ unsigned short As[2 * 2048];
    const int tid = threadIdx.x, bm = blockIdx.x;
    const int lane = tid & 63, wid = tid >> 6;
    const int lane16 = lane & 15, g = lane >> 4;

    f32x4 acc[4][8];
    gemm_pipe_64x512(hidden + (size_t)bm * 64 * KDIM, w2img, As, acc);

    #pragma unroll
    for (int j = 0; j < 8; ++j) {
        int col = wid * 128 + j * 16 + lane16;
        float bb = b2[col];
        #pragma unroll
        for (int i = 0; i < 4; ++i)
            #pragma unroll
            for (int r = 0; r < 4; ++r) {
                int row = bm * 64 + i * 16 + g * 4 + r;
                h2[(size_t)row * UDIM + col] = acc[i][j][r] + bb;
            }
    }
}

// ---------------------------------------------------------------------------
// Kernel B (fused): block = 1 batch. h1 = feat@W1 -> tanh(.+b1+h2)·Wv
// -> softmax(S=64) -> context = sum_s w_s * feat[b,s,:]
// ---------------------------------------------------------------------------
__global__ __launch_bounds__(256, 2)
void fused_all_kernel(const float* __restrict__ feat,
                      const char* __restrict__ w1img,
                      const float* __restrict__ h2,
                      const float* __restrict__ b1,
                      const float* __restrict__ wv,
                      float* __restrict__ out) {
    __shared__ unsigned short As[2 * 2048];
    __shared__ float spl[64 * 4];
    __shared__ float wsm[64];

    const int tid = threadIdx.x;
    const int bm = blockIdx.x;                // batch index 0..2047
    const int lane = tid & 63, wid = tid >> 6;
    const int lane16 = lane & 15, g = lane >> 4;

    f32x4 acc[4][8];
    gemm_pipe_64x512(feat + (size_t)bm * 64 * KDIM, w1img, As, acc);

    // epilogue constants loaded after the pipeline (keeps loop regs low;
    // pipeline ended on vmcnt(0) so the ledger is clean)
    float hhv[8], wvv[8];
    #pragma unroll
    for (int j = 0; j < 8; ++j) {
        int u = wid * 128 + j * 16 + lane16;
        hhv[j] = b1[u] + h2[(size_t)bm * UDIM + u];
        wvv[j] = wv[u];
    }

    // ---- scores: tanh + dot(Wv) over this wave's 128 cols ----
    #pragma unroll
    for (int i = 0; i < 4; ++i) {
        #pragma unroll
        for (int r = 0; r < 4; ++r) {
            float s = 0.f;
            #pragma unroll
            for (int j = 0; j < 8; ++j) {
                float h = acc[i][j][r] + hhv[j];
                float ex = __expf(2.f * h);
                float th = 1.f - 2.f * __builtin_amdgcn_rcpf(ex + 1.f);
                s += th * wvv[j];
            }
            s += __shfl_xor(s, 1); s += __shfl_xor(s, 2);
            s += __shfl_xor(s, 4); s += __shfl_xor(s, 8);
            if (lane16 == 0)
                spl[(i * 16 + g * 4 + r) * 4 + wid] = s;
        }
    }
    __syncthreads();

    // ---- softmax over S=64 (bv shift is a softmax no-op) ----
    if (tid < 64) {
        float s = (spl[tid * 4 + 0] + spl[tid * 4 + 1]) +
                  (spl[tid * 4 + 2] + spl[tid * 4 + 3]);
        float m = s;
        #pragma unroll
        for (int off = 32; off; off >>= 1) m = fmaxf(m, __shfl_xor(m, off));
        float e = __expf(s - m);
        float sum = e;
        #pragma unroll
        for (int off = 32; off; off >>= 1) sum += __shfl_xor(sum, off);
        wsm[tid] = e / sum;
    }
    __syncthreads();

    // ---- context: 256 threads x float2 over 512 cols, 64 seq steps ----
    {
        const float2* f2 = (const float2*)(feat + (size_t)bm * 64 * KDIM);
        float ax = 0.f, ay = 0.f;
        #pragma unroll 8
        for (int s = 0; s < 64; ++s) {
            float w = wsm[s];
            float2 v = f2[s * 256 + tid];
            ax += w * v.x; ay += w * v.y;
        }
        ((float2*)out)[(size_t)bm * 256 + tid] = make_float2(ax, ay);
    }
}

// ---------------------------------------------------------------------------
extern "C" void kernel_launch(void* const* d_in, const int* in_sizes, int n_in,
                              void* d_out, int out_size, void* d_ws, size_t ws_size,
                              hipStream_t stream) {
    (void)in_sizes; (void)n_in; (void)out_size; (void)ws_size;
    const float* feat   = (const float*)d_in[0];   // [2048,64,512]
    const float* hidden = (const float*)d_in[1];   // [2048,512]
    const float* W1     = (const float*)d_in[2];   // [512,512]
    const float* b1     = (const float*)d_in[3];   // [512]
    const float* W2     = (const float*)d_in[4];   // [512,512]
    const float* b2     = (const float*)d_in[5];   // [512]
    const float* Wv     = (const float*)d_in[6];   // [512,1]
    // d_in[7] = bv: softmax shift-invariant, unused.
    float* out = (float*)d_out;                    // [2048,512]

    char* ws = (char*)d_ws;
    unsigned short* w1img = (unsigned short*)(ws);            // 512 KB
    unsigned short* w2img = (unsigned short*)(ws + 524288);   // 512 KB
    float* h2 = (float*)(ws + 1048576);                       // 4 MB

    convert_w_kernel<<<dim3(512, 2), dim3(256), 0, stream>>>(W1, W2, w1img, w2img);
    h2_gemm_f16_kernel<<<dim3(32), dim3(256), 0, stream>>>(hidden, (const char*)w2img, b2, h2);
    fused_all_kernel<<<dim3(2048), dim3(256), 0, stream>>>(feat, (const char*)w1img, h2, b1, Wv, out);
}

// Round 5
// 149.562 us; speedup vs baseline: 3.6428x; 1.0370x over previous
//
#include <hip/hip_runtime.h>

typedef _Float16 f16x8 __attribute__((ext_vector_type(8)));
typedef unsigned short u16x4 __attribute__((ext_vector_type(4)));
typedef float f32x4 __attribute__((ext_vector_type(4)));

#define VMWAIT(N) asm volatile("s_waitcnt vmcnt(" #N ")" ::: "memory")

// ---------------------------------------------------------------------------
// Kernel 0: W [K,U] f32 -> fp16 image, layout [ktile=k>>5][u][k&31] u16.
// ---------------------------------------------------------------------------
__global__ void convert_w_kernel(const float* __restrict__ w1,
                                 const float* __restrict__ w2,
                                 unsigned short* __restrict__ w1img,
                                 unsigned short* __restrict__ w2img) {
    int u = blockIdx.x;                           // 0..511
    int k = threadIdx.x + blockIdx.y * 256;       // 0..511
    size_t idx = (size_t)(k >> 5) * 16384 + (size_t)u * 32 + (k & 31);
    _Float16 h1 = (_Float16)w1[(size_t)k * 512 + u];
    _Float16 h2 = (_Float16)w2[(size_t)k * 512 + u];
    w1img[idx] = __builtin_bit_cast(unsigned short, h1);
    w2img[idx] = __builtin_bit_cast(unsigned short, h2);
}

// ---------------------------------------------------------------------------
// Stage 64x512 fp32 -> LDS fp16, tiled layout [kstep][row][32] with XOR
// swizzle: byte = kstep*4096 + row*64 + (((kslot ^ ((row>>1)&3))<<4) | (k&7)*2.
// 256 threads, rolling 2x4 dwordx4 pipeline (8 loads in flight).
// ---------------------------------------------------------------------------
__device__ __forceinline__ void stage_a64(const float* __restrict__ src,
                                          char* As, int tid) {
    const int row = tid >> 2, q = tid & 3;
    const float* p = src + (size_t)row * 512 + q * 4;
    const int sw2 = ((row >> 1) & 3) << 4;
    char* wb = As + row * 64;
    float4 va[4], vb[4];
#define AISS(V, G) { _Pragma("unroll") \
    for (int j_ = 0; j_ < 4; ++j_) V[j_] = *(const float4*)(p + ((G) * 4 + j_) * 16); }
#define APRC(V, G) { _Pragma("unroll") \
    for (int j_ = 0; j_ < 4; ++j_) { \
        const int i_ = (G) * 4 + j_; \
        u16x4 h_; \
        h_[0] = __builtin_bit_cast(unsigned short, (_Float16)V[j_].x); \
        h_[1] = __builtin_bit_cast(unsigned short, (_Float16)V[j_].y); \
        h_[2] = __builtin_bit_cast(unsigned short, (_Float16)V[j_].z); \
        h_[3] = __builtin_bit_cast(unsigned short, (_Float16)V[j_].w); \
        *(u16x4*)(wb + (i_ >> 1) * 4096 + ((q * 8 + (i_ & 1) * 32) ^ sw2)) = h_; } }
    AISS(va, 0); AISS(vb, 1);
    VMWAIT(4); APRC(va, 0); AISS(va, 2);
    VMWAIT(4); APRC(vb, 1); AISS(vb, 3);
    VMWAIT(4); APRC(va, 2); AISS(va, 4);
    VMWAIT(4); APRC(vb, 3); AISS(vb, 5);
    VMWAIT(4); APRC(va, 4); AISS(va, 6);
    VMWAIT(4); APRC(vb, 5); AISS(vb, 7);
    VMWAIT(4); APRC(va, 6);
    VMWAIT(0); APRC(vb, 7);
#undef AISS
#undef APRC
}

// ---------------------------------------------------------------------------
// Barrier-free 64x64 chunk GEMM (K=512, 16 steps of BK=32). A from LDS
// (double-buffered ds_read_b128), B global->reg from L2-hot image, 2-deep
// prefetch. VM FIFO holds only B loads: one VMWAIT(4) per step.
// ---------------------------------------------------------------------------
__device__ __forceinline__ void chunk_gemm(const char* __restrict__ bcol,
                                           const char* As, const int* aoff,
                                           f32x4 acc[4][4]) {
    f16x8 brA[4], brB[4], afA[4], afB[4];
    #pragma unroll
    for (int i = 0; i < 4; ++i)
        #pragma unroll
        for (int j = 0; j < 4; ++j) acc[i][j] = (f32x4){0.f, 0.f, 0.f, 0.f};
    #pragma unroll
    for (int j = 0; j < 4; ++j) brA[j] = *(const f16x8*)(bcol + j * 1024);
    #pragma unroll
    for (int j = 0; j < 4; ++j) brB[j] = *(const f16x8*)(bcol + 32768 + j * 1024);
    #pragma unroll
    for (int i = 0; i < 4; ++i) afA[i] = *(const f16x8*)(As + aoff[i]);

    #pragma unroll
    for (int tt = 0; tt < 8; ++tt) {
        const int t0 = 2 * tt, t1 = t0 + 1;
        if (t0 < 15) {
            #pragma unroll
            for (int i = 0; i < 4; ++i)
                afB[i] = *(const f16x8*)(As + t1 * 4096 + aoff[i]);
        }
        VMWAIT(4);                                  // B(t0) landed
        #pragma unroll
        for (int i = 0; i < 4; ++i)
            #pragma unroll
            for (int j = 0; j < 4; ++j)
                acc[i][j] = __builtin_amdgcn_mfma_f32_16x16x32_f16(afA[i], brA[j], acc[i][j], 0, 0, 0);
        if (t0 < 14) {
            #pragma unroll
            for (int j = 0; j < 4; ++j)
                brA[j] = *(const f16x8*)(bcol + (t0 + 2) * 32768 + j * 1024);
        }
        if (t1 < 15) {
            #pragma unroll
            for (int i = 0; i < 4; ++i)
                afA[i] = *(const f16x8*)(As + (t1 + 1) * 4096 + aoff[i]);
        }
        if (t1 < 14) { VMWAIT(4); } else { VMWAIT(0); }
        #pragma unroll
        for (int i = 0; i < 4; ++i)
            #pragma unroll
            for (int j = 0; j < 4; ++j)
                acc[i][j] = __builtin_amdgcn_mfma_f32_16x16x32_f16(afB[i], brB[j], acc[i][j], 0, 0, 0);
        if (t1 < 14) {
            #pragma unroll
            for (int j = 0; j < 4; ++j)
                brB[j] = *(const f16x8*)(bcol + (t1 + 2) * 32768 + j * 1024);
        }
    }
}

// ---------------------------------------------------------------------------
// Kernel A: h2 = hidden @ W2 + b2  (32 blocks, barrier-light structure)
// ---------------------------------------------------------------------------
__global__ __launch_bounds__(256, 2)
void h2_gemm_kernel(const float* __restrict__ hidden,
                    const char* __restrict__ w2img,
                    const float* __restrict__ b2,
                    float* __restrict__ h2o) {
    __shared__ char As[65536];
    const int tid = threadIdx.x, bm = blockIdx.x;
    const int lane = tid & 63, wid = tid >> 6;
    const int lane16 = lane & 15, g = lane >> 4;
    stage_a64(hidden + (size_t)bm * 32768, As, tid);
    __syncthreads();
    const int swA = (lane16 >> 1) & 3;
    int aoff[4];
    #pragma unroll
    for (int i = 0; i < 4; ++i)
        aoff[i] = (i * 16 + lane16) * 64 + ((g ^ swA) << 4);
    #pragma unroll
    for (int c = 0; c < 2; ++c) {
        const char* bcol = w2img + (size_t)(wid * 128 + c * 64 + lane16) * 64 + g * 16;
        f32x4 acc[4][4];
        chunk_gemm(bcol, As, aoff, acc);
        #pragma unroll
        for (int j = 0; j < 4; ++j) {
            int col = wid * 128 + c * 64 + j * 16 + lane16;
            float bb = b2[col];
            #pragma unroll
            for (int i = 0; i < 4; ++i)
                #pragma unroll
                for (int r = 0; r < 4; ++r)
                    h2o[(size_t)(bm * 64 + i * 16 + g * 4 + r) * 512 + col] = acc[i][j][r] + bb;
        }
    }
}

// ---------------------------------------------------------------------------
// Kernel B (fused): block = 1 batch. Stage A once -> barrier-free chunked
// fp16 MFMA -> tanh(.+b1+h2)·Wv -> softmax(S=64) -> context from LDS A.
// ---------------------------------------------------------------------------
__global__ __launch_bounds__(256, 2)
void fused_all_kernel(const float* __restrict__ feat,
                      const char* __restrict__ w1img,
                      const float* __restrict__ h2,
                      const float* __restrict__ b1,
                      const float* __restrict__ wv,
                      float* __restrict__ out) {
    __shared__ char As[65536];
    __shared__ float spl[256];
    __shared__ float wsm[64];
    const int tid = threadIdx.x, bm = blockIdx.x;
    const int lane = tid & 63, wid = tid >> 6;
    const int lane16 = lane & 15, g = lane >> 4;

    stage_a64(feat + (size_t)bm * 32768, As, tid);
    __syncthreads();

    // per-wave epilogue constants; VMWAIT(0) below re-cleans the ledger
    float hhv[8], wvv[8];
    #pragma unroll
    for (int j = 0; j < 8; ++j) {
        int u = wid * 128 + j * 16 + lane16;
        hhv[j] = b1[u] + h2[(size_t)bm * 512 + u];
        wvv[j] = wv[u];
    }
    VMWAIT(0);

    const int swA = (lane16 >> 1) & 3;
    int aoff[4];
    #pragma unroll
    for (int i = 0; i < 4; ++i)
        aoff[i] = (i * 16 + lane16) * 64 + ((g ^ swA) << 4);

    float sacc[16];
    #pragma unroll
    for (int x = 0; x < 16; ++x) sacc[x] = 0.f;

    #pragma unroll
    for (int c = 0; c < 2; ++c) {
        const char* bcol = w1img + (size_t)(wid * 128 + c * 64 + lane16) * 64 + g * 16;
        f32x4 acc[4][4];
        chunk_gemm(bcol, As, aoff, acc);
        #pragma unroll
        for (int i = 0; i < 4; ++i)
            #pragma unroll
            for (int r = 0; r < 4; ++r) {
                float s = 0.f;
                #pragma unroll
                for (int j = 0; j < 4; ++j) {
                    float h = acc[i][j][r] + hhv[c * 4 + j];
                    float ex = __expf(2.f * h);
                    s += (1.f - 2.f * __builtin_amdgcn_rcpf(ex + 1.f)) * wvv[c * 4 + j];
                }
                sacc[i * 4 + r] += s;
            }
    }

    // cross-wave score reduce
    #pragma unroll
    for (int i = 0; i < 4; ++i)
        #pragma unroll
        for (int r = 0; r < 4; ++r) {
            float s = sacc[i * 4 + r];
            s += __shfl_xor(s, 1); s += __shfl_xor(s, 2);
            s += __shfl_xor(s, 4); s += __shfl_xor(s, 8);
            if (lane16 == 0) spl[(i * 16 + g * 4 + r) * 4 + wid] = s;
        }
    __syncthreads();

    // softmax over S=64 (bv shift is a softmax no-op)
    if (tid < 64) {
        float s = (spl[tid * 4 + 0] + spl[tid * 4 + 1]) +
                  (spl[tid * 4 + 2] + spl[tid * 4 + 3]);
        float m = s;
        #pragma unroll
        for (int off = 32; off; off >>= 1) m = fmaxf(m, __shfl_xor(m, off));
        float e = __expf(s - m);
        float sum = e;
        #pragma unroll
        for (int off = 32; off; off >>= 1) sum += __shfl_xor(sum, off);
        wsm[tid] = e / sum;
    }
    __syncthreads();

    // context from LDS fp16 A: thread owns cols {2*tid, 2*tid+1}
    {
        const int cseg = (tid >> 4) * 4096;     // (2*tid)>>5 k-tile
        const int cin = (tid & 15) * 4;         // ((2*tid)&31)*2 bytes
        float ax = 0.f, ay = 0.f;
        #pragma unroll 8
        for (int s = 0; s < 64; ++s) {
            unsigned v = *(const unsigned*)(As + cseg + s * 64 +
                                            (cin ^ (((s >> 1) & 3) << 4)));
            float w = wsm[s];
            ax += w * (float)__builtin_bit_cast(_Float16, (unsigned short)(v & 0xffffu));
            ay += w * (float)__builtin_bit_cast(_Float16, (unsigned short)(v >> 16));
        }
        ((float2*)out)[(size_t)bm * 256 + tid] = make_float2(ax, ay);
    }
}

// ---------------------------------------------------------------------------
extern "C" void kernel_launch(void* const* d_in, const int* in_sizes, int n_in,
                              void* d_out, int out_size, void* d_ws, size_t ws_size,
                              hipStream_t stream) {
    (void)in_sizes; (void)n_in; (void)out_size; (void)ws_size;
    const float* feat   = (const float*)d_in[0];   // [2048,64,512]
    const float* hidden = (const float*)d_in[1];   // [2048,512]
    const float* W1     = (const float*)d_in[2];   // [512,512]
    const float* b1     = (const float*)d_in[3];   // [512]
    const float* W2     = (const float*)d_in[4];   // [512,512]
    const float* b2     = (const float*)d_in[5];   // [512]
    const float* Wv     = (const float*)d_in[6];   // [512,1]
    // d_in[7] = bv: softmax shift-invariant, unused.
    float* out = (float*)d_out;                    // [2048,512]

    char* ws = (char*)d_ws;
    unsigned short* w1img = (unsigned short*)(ws);            // 512 KB
    unsigned short* w2img = (unsigned short*)(ws + 524288);   // 512 KB
    float* h2 = (float*)(ws + 1048576);                       // 4 MB

    convert_w_kernel<<<dim3(512, 2), dim3(256), 0, stream>>>(W1, W2, w1img, w2img);
    h2_gemm_kernel<<<dim3(32), dim3(256), 0, stream>>>(hidden, (const char*)w2img, b2, h2);
    fused_all_kernel<<<dim3(2048), dim3(256), 0, stream>>>(feat, (const char*)w1img, h2, b1, Wv, out);
}